// Round 1
// baseline (76.306 us; speedup 1.0000x reference)
//
#include <hip/hip_runtime.h>

// Problem constants
#define NQ 20
#define DIMQ (1 << NQ)          // 2^20
#define NB 16                   // BATCH
#define NT 4                    // N_TERMS
#define RBITS 15                // low bits untouched by gates
#define NCOL (1 << (RBITS + 4)) // 2^15 r-values * 16 batches = 524288 columns

// ---------------------------------------------------------------------------
// Kernel A: U[k,b] = exp(-i * H_k * t_{k,b}),  H_k = 0.5*(A + A^H), A = Hr + i Hi
// 256 threads: 64 tasks (k,b) x 4 rows. Scaling (2^-6) + 10-term Taylor + 6 squarings.
// Output layout in ws: u_re[(k*16 + i*4 + j)*16 + b], u_im at +1024 floats.
// ---------------------------------------------------------------------------
__global__ __launch_bounds__(256) void compute_u_kernel(
    const float* __restrict__ Hre, const float* __restrict__ Him,
    const float* __restrict__ tevo, float* __restrict__ uout) {
  __shared__ float er_s[64][4][4];
  __shared__ float ei_s[64][4][4];

  const int tid  = threadIdx.x;   // 0..255
  const int task = tid >> 2;      // 0..63
  const int row  = tid & 3;       // 0..3
  const int k    = task >> 4;     // 0..3
  const int b    = task & 15;     // 0..15

  // Load full A for term k (each thread redundantly; tiny)
  float Ar[4][4], Ai[4][4];
#pragma unroll
  for (int i = 0; i < 4; i++) {
#pragma unroll
    for (int j = 0; j < 4; j++) {
      Ar[i][j] = Hre[k * 16 + i * 4 + j];
      Ai[i][j] = Him[k * 16 + i * 4 + j];
    }
  }
  const float t = tevo[k * NB + b];
  const float ts = t * (1.0f / 64.0f);  // scale 2^-6 folded in

  // G = -i * H * ts ; H = 0.5*(A + A^H)
  // Hr[i][j] = 0.5*(Ar[i][j]+Ar[j][i]) ; Hi[i][j] = 0.5*(Ai[i][j]-Ai[j][i])
  // G_re = ts*Hi ; G_im = -ts*Hr
  float Gr[4][4], Gi[4][4];
#pragma unroll
  for (int i = 0; i < 4; i++) {
#pragma unroll
    for (int j = 0; j < 4; j++) {
      const float hr = 0.5f * (Ar[i][j] + Ar[j][i]);
      const float hi = 0.5f * (Ai[i][j] - Ai[j][i]);
      Gr[i][j] = ts * hi;
      Gi[i][j] = -ts * hr;
    }
  }

  // Taylor: E = I + sum_{m=1..10} G^m/m!   (row `row` only; full G in regs)
  float Er[4], Ei[4], Tr[4], Ti[4];
#pragma unroll
  for (int j = 0; j < 4; j++) {
    Er[j] = (j == row) ? 1.0f : 0.0f;
    Ei[j] = 0.0f;
    Tr[j] = Er[j];
    Ti[j] = 0.0f;
  }
#pragma unroll
  for (int m = 1; m <= 10; m++) {
    const float inv = 1.0f / (float)m;
    float nr[4], ni[4];
#pragma unroll
    for (int j = 0; j < 4; j++) {
      float ar = 0.0f, ai = 0.0f;
#pragma unroll
      for (int p = 0; p < 4; p++) {
        ar += Tr[p] * Gr[p][j] - Ti[p] * Gi[p][j];
        ai += Tr[p] * Gi[p][j] + Ti[p] * Gr[p][j];
      }
      nr[j] = ar * inv;
      ni[j] = ai * inv;
    }
#pragma unroll
    for (int j = 0; j < 4; j++) {
      Tr[j] = nr[j]; Ti[j] = ni[j];
      Er[j] += nr[j]; Ei[j] += ni[j];
    }
  }

  // 6 squarings via LDS (uniform trip count -> barriers are safe)
  for (int q = 0; q < 6; q++) {
    __syncthreads();
#pragma unroll
    for (int j = 0; j < 4; j++) {
      er_s[task][row][j] = Er[j];
      ei_s[task][row][j] = Ei[j];
    }
    __syncthreads();
    float nr[4], ni[4];
#pragma unroll
    for (int j = 0; j < 4; j++) {
      float ar = 0.0f, ai = 0.0f;
#pragma unroll
      for (int p = 0; p < 4; p++) {
        ar += Er[p] * er_s[task][p][j] - Ei[p] * ei_s[task][p][j];
        ai += Er[p] * ei_s[task][p][j] + Ei[p] * er_s[task][p][j];
      }
      nr[j] = ar; ni[j] = ai;
    }
#pragma unroll
    for (int j = 0; j < 4; j++) { Er[j] = nr[j]; Ei[j] = ni[j]; }
  }

  // Store U rows: layout [k][i][j][b], b contiguous
#pragma unroll
  for (int j = 0; j < 4; j++) {
    uout[(k * 16 + row * 4 + j) * 16 + b] = Er[j];
    uout[1024 + (k * 16 + row * 4 + j) * 16 + b] = Ei[j];
  }
}

// ---------------------------------------------------------------------------
// Kernel B: out[g,r,b] = sum_k sum_j U[k,b][i(g,k)][j] * s[g'(g,k,j), r, b]
// One thread per column (r,b). 32 complex in regs, 32 complex acc, 4 terms.
// col = r*16+b ; state offset = col + g*2^19 floats.
// ---------------------------------------------------------------------------
__global__ __launch_bounds__(256) void apply_gates_kernel(
    const float* __restrict__ sre, const float* __restrict__ sim,
    const float* __restrict__ u, float* __restrict__ out) {
  __shared__ float ul[2048];
  const int tid = threadIdx.x;
  // stage U table (8 KiB) to LDS
  {
    const float4* u4 = (const float4*)u;
    float4* ul4 = (float4*)ul;
    ul4[tid] = u4[tid];
    ul4[tid + 256] = u4[tid + 256];
  }
  __syncthreads();

  const int b = tid & 15;
  const int col = blockIdx.x * 256 + tid;  // r*16 + b, r = col>>4

  float s_re[32], s_im[32];
#pragma unroll
  for (int g = 0; g < 32; g++) {
    const int off = col + (g << 19);
    s_re[g] = sre[off];
    s_im[g] = sim[off];
  }

  float o_re[32], o_im[32];
#pragma unroll
  for (int g = 0; g < 32; g++) { o_re[g] = 0.0f; o_im[g] = 0.0f; }

#pragma unroll
  for (int k = 0; k < 4; k++) {
    const int sh = 3 - k;  // low bit position of the gate's pair within g
    float ur[4][4], ui[4][4];
#pragma unroll
    for (int i = 0; i < 4; i++) {
#pragma unroll
      for (int j = 0; j < 4; j++) {
        ur[i][j] = ul[((k * 16 + i * 4 + j) << 4) + b];
        ui[i][j] = ul[1024 + ((k * 16 + i * 4 + j) << 4) + b];
      }
    }
#pragma unroll
    for (int g = 0; g < 32; g++) {
      const int i = (g >> sh) & 3;
      const int gb = g & ~(3 << sh);
#pragma unroll
      for (int j = 0; j < 4; j++) {
        const int src = gb | (j << sh);
        o_re[g] += ur[i][j] * s_re[src] - ui[i][j] * s_im[src];
        o_im[g] += ur[i][j] * s_im[src] + ui[i][j] * s_re[src];
      }
    }
  }

#pragma unroll
  for (int g = 0; g < 32; g++) {
    const int off = col + (g << 19);
    out[off] = o_re[g];                  // real part
    out[off + (1 << 24)] = o_im[g];      // imag part (DIM*NB = 2^24 floats)
  }
}

extern "C" void kernel_launch(void* const* d_in, const int* in_sizes, int n_in,
                              void* d_out, int out_size, void* d_ws, size_t ws_size,
                              hipStream_t stream) {
  const float* Hre  = (const float*)d_in[0];
  const float* Him  = (const float*)d_in[1];
  const float* tevo = (const float*)d_in[2];
  const float* sre  = (const float*)d_in[3];
  const float* sim  = (const float*)d_in[4];
  float* out = (float*)d_out;
  float* u   = (float*)d_ws;  // 2048 floats = 8 KiB

  compute_u_kernel<<<1, 256, 0, stream>>>(Hre, Him, tevo, u);
  apply_gates_kernel<<<NCOL / 256, 256, 0, stream>>>(sre, sim, u, out);
}